// Round 10
// baseline (395.606 us; speedup 1.0000x reference)
//
#include <hip/hip_runtime.h>
#include <hip/hip_bf16.h>
#include <math.h>

#define Gn 16000
#define Bn 4096
#define Ln 64
#define Sn 20000
#define GT 320            // genes per tile (1280B contiguous per b-row)
#define NGT 50            // Gn/GT
#define BT 16             // b-rows per tile
#define XP 324            // x-tile LDS pitch (dwords); 324%32=4 -> 2-way banks (free)
#define GENE_BLOCKS 4000  // (Gn*64)/256
#define SPOT_BLOCKS 1024  // (Bn*64)/256

typedef __attribute__((ext_vector_type(8))) short bf16x8;   // 8 bf16 = 4 VGPRs
typedef __attribute__((ext_vector_type(4))) float f32x4;    // MFMA C/D

// ---------- device math helpers ----------

__device__ __forceinline__ float softplus_precise(float z) {
    return fmaxf(z, 0.0f) + log1pf(__expf(-fabsf(z)));
}

// accurate lgamma for z>0 (shift-8 Stirling), used only for the 100-entry table
__device__ __forceinline__ float lgamma_pos8(float z) {
    float p = z * (z + 1.f) * (z + 2.f) * (z + 3.f)
                * (z + 4.f) * (z + 5.f) * (z + 6.f) * (z + 7.f);
    float w = z + 8.f;
    return (w - 0.5f) * __logf(w) - w + 0.9189385332046727f
           + __fdividef(1.0f, 12.0f * w) - __logf(p);
}

__device__ __forceinline__ unsigned short f2bf(float f) {
    union { float f; unsigned int u; } v; v.f = f;
    unsigned int r = v.u + 0x7fff + ((v.u >> 16) & 1);   // RNE
    return (unsigned short)(r >> 16);
}

// ---------- fused precompute (R9-verified, verbatim) ----------

__global__ void prep_fused(const float* __restrict__ W,
                           const float* __restrict__ px_o,
                           const float* __restrict__ eta,
                           const float* __restrict__ beta,
                           const float* __restrict__ V,
                           const int*   __restrict__ ind_x,
                           unsigned short* __restrict__ rhB,
                           float* __restrict__ lsp1,
                           float* __restrict__ lsn,
                           float* __restrict__ eps,
                           unsigned short* __restrict__ vBg,
                           float* __restrict__ v64,
                           float* __restrict__ prior_part) {
    const int bid = blockIdx.x;
    const int tid = threadIdx.x;
    if (bid < GENE_BLOCKS) {
        int idx = bid * 256 + tid;   // Gn*64 total, exact
        int g = idx >> 6;
        float bsp = softplus_precise(beta[g]);
        rhB[idx] = f2bf(bsp * softplus_precise(W[idx]));   // W row-major [G][L]
        float s = 0.f;
        if (idx < Gn) {
            eps[idx] = softplus_precise(eta[idx]);
            float o = px_o[idx];
            lsp1[idx] = -softplus_precise(-o) - 1.0f;   // log_sigmoid(o) - 1
            lsn[idx]  = -softplus_precise(o);           // log_sigmoid(-o)
            float e = eta[idx];
            s = 0.9189385332046727f + 0.5f * e * e;     // -log N(eta;0,1)
        }
        if (bid < 64) {
            #pragma unroll
            for (int off = 32; off; off >>= 1) s += __shfl_xor(s, off, 64);
            __shared__ float red[4];
            if ((tid & 63) == 0) red[tid >> 6] = s;
            __syncthreads();
            if (tid == 0) prior_part[bid] = red[0] + red[1] + red[2] + red[3];
        }
    } else {
        int idx = (bid - GENE_BLOCKS) * 256 + tid;   // Bn*64 total, exact
        int b = idx >> 6, l = idx & 63;
        int s = ind_x[b];
        vBg[idx] = f2bf(softplus_precise(V[l * Sn + s]));
        if (idx < Bn) {
            int s2 = ind_x[idx];
            v64[idx] = softplus_precise(V[Ln * Sn + s2]);
        }
    }
}

// ---------- main kernel: 16b x 320g tile, large-chunk x reads ----------
//
// term = lgamma(x+r) - lgamma(r) - lgamma(x+1) + x*lsp + r*lsn
//      ~= (s-0.5)ln s - (r-0.5)ln r + x*(lsp-1) + r*lsn - lfact[x],  s = r+x
//
// v11: clean-room aspect flip (the R6 theory without R6's unverified parts):
//   * x staged as plain int32 into LDS [16][XP]: per b-row ONE 1280B
//     contiguous span -> 4x fewer DRAM streams, 5x larger chunks than v2.
//   * M=16: one m-block shared by all 4 waves (A-frags from vBg rows b0..b0+15,
//     v2-verified fragment math); waves split the 320 genes (5 nb each).
//   * rh/lsp1/lsn/eps read straight from L2 (rhB 2MB resident; no sB tile).
//   * per-nb fused MFMA+epilogue (R5-verified): one f32x4 live accumulator.
//   * cross-wave row-sum via pred[4][16] (re-derived 3x; elementary).

__global__ __launch_bounds__(256, 4) void main_kernel(
    const int*            __restrict__ x,
    const unsigned short* __restrict__ rhB,
    const unsigned short* __restrict__ vBg,
    const float*          __restrict__ v64,
    const float*          __restrict__ lsp1g,
    const float*          __restrict__ lsng,
    const float*          __restrict__ epsg,
    float*                __restrict__ partial) {
    __shared__ __align__(16) int sX[BT * XP];   // 20736 B
    __shared__ float lfact[100];
    __shared__ float pred[4][16];

    const int tid  = threadIdx.x;
    const int wave = tid >> 6, lane = tid & 63;
    const int quad = lane >> 4, ln = lane & 15;
    const int gt = blockIdx.x;        // gt-fastest (verified ordering)
    const int b0 = blockIdx.y * BT;
    const int g0 = gt * GT;

    // ---- stage x: 1280 int4s; inst i reads 1024B contiguous (runs of 1280B/row) ----
    #pragma unroll
    for (int i = 0; i < 5; ++i) {
        int F   = i * 256 + tid;        // int4 index in [0,1280)
        int row = F / 80;               // 80 int4s per row
        int c4  = F - row * 80;
        int4 v = *(const int4*)&x[(size_t)(b0 + row) * Gn + g0 + c4 * 4];
        *(int4*)&sX[row * XP + c4 * 4] = v;
    }

    // A-fragments (v tile rows b0..b0+15) + per-row v64 (v2-verified mapping)
    bf16x8 av0 = *(const bf16x8*)&vBg[(b0 + ln) * 64 + quad * 8];
    bf16x8 av1 = *(const bf16x8*)&vBg[(b0 + ln) * 64 + 32 + quad * 8];
    float4 vv4 = *(const float4*)&v64[b0 + quad * 4];
    float vvr[4] = {vv4.x, vv4.y, vv4.z, vv4.w};

    if (tid < 100) lfact[tid] = lgamma_pos8((float)tid + 1.0f);

    __syncthreads();

    // ---- fused MFMA + NB epilogue; wave handles genes [wave*80, wave*80+80) ----
    float rowacc[4] = {0.f, 0.f, 0.f, 0.f};
    #pragma unroll
    for (int nb = 0; nb < 5; ++nb) {
        const int gl = wave * 80 + nb * 16 + ln;   // local gene (this lane's C col)
        const int gg = g0 + gl;                    // absolute gene
        const unsigned short* rrow = &rhB[(size_t)gg * 64];   // L2-resident
        bf16x8 bf0 = *(const bf16x8*)&rrow[quad * 8];
        bf16x8 bf1 = *(const bf16x8*)&rrow[32 + quad * 8];
        f32x4 a = (f32x4){0.f, 0.f, 0.f, 0.f};
        a = __builtin_amdgcn_mfma_f32_16x16x32_bf16(av0, bf0, a, 0, 0, 0);
        a = __builtin_amdgcn_mfma_f32_16x16x32_bf16(av1, bf1, a, 0, 0, 0);

        const float lsp1v = lsp1g[gg];
        const float lsnv  = lsng[gg];
        const float ev    = epsg[gg];
        #pragma unroll
        for (int r = 0; r < 4; ++r) {
            const int row = quad * 4 + r;          // C row (m index)
            const int xi  = sX[row * XP + gl];
            const float rr = fmaf(ev, vvr[r], a[r]);   // + eps*v64, fp32
            const float xf = (float)xi;
            const float s  = rr + xf;
            float tt = fmaf(s - 0.5f, __logf(s), -lfact[xi]);
            tt = fmaf(-(rr - 0.5f), __logf(rr), tt);
            tt = fmaf(xf, lsp1v, tt);
            tt = fmaf(rr, lsnv, tt);
            rowacc[r] += tt;
        }
    }

    // reduce over the 16 gene-lanes of each quad, then fold the 4 waves via LDS
    #pragma unroll
    for (int r = 0; r < 4; ++r) {
        float v = rowacc[r];
        v += __shfl_xor(v, 1, 64);
        v += __shfl_xor(v, 2, 64);
        v += __shfl_xor(v, 4, 64);
        v += __shfl_xor(v, 8, 64);
        if (ln == 0) pred[wave][quad * 4 + r] = v;
    }
    __syncthreads();
    if (tid < BT) {
        float s = pred[0][tid] + pred[1][tid] + pred[2][tid] + pred[3][tid];
        partial[(size_t)gt * Bn + b0 + tid] = s;
    }
}

// fold partial[NGT][4096] -> out[b] (negated); block 0 finalizes scalar slots.
// Pure stores, idempotent, no memset needed (R9-verified scheme).
__global__ __launch_bounds__(256) void reduce_kernel(const float* __restrict__ partial,
                                                     const float* __restrict__ prior_part,
                                                     float* __restrict__ out) {
    int b = blockIdx.x * 256 + threadIdx.x;
    float s0 = 0.f, s1 = 0.f, s2 = 0.f, s3 = 0.f, s4 = 0.f;
    for (int i = 0; i < NGT; i += 5) {
        s0 += partial[(size_t)(i + 0) * Bn + b];
        s1 += partial[(size_t)(i + 1) * Bn + b];
        s2 += partial[(size_t)(i + 2) * Bn + b];
        s3 += partial[(size_t)(i + 3) * Bn + b];
        s4 += partial[(size_t)(i + 4) * Bn + b];
    }
    out[b] = -(s0 + s1 + s2 + s3 + s4);

    if (blockIdx.x == 0) {
        int tid = threadIdx.x;
        if (tid < 64) {   // wave 0: fold the 64 prior partials
            float s = prior_part[tid];
            #pragma unroll
            for (int off = 32; off; off >>= 1) s += __shfl_xor(s, off, 64);
            if (tid == 0) {
                out[Bn]     = 0.0f;   // second ref output is literal 0
                out[Bn + 1] = s;      // -sum log N(eta;0,1)
            }
        }
    }
}

// ---------- launch: 3 dispatches ----------

extern "C" void kernel_launch(void* const* d_in, const int* in_sizes, int n_in,
                              void* d_out, int out_size, void* d_ws, size_t ws_size,
                              hipStream_t stream) {
    const int*   x     = (const int*)d_in[0];
    const int*   ind_x = (const int*)d_in[2];
    const float* W     = (const float*)d_in[3];
    const float* px_o  = (const float*)d_in[4];
    const float* eta   = (const float*)d_in[5];
    const float* V     = (const float*)d_in[6];
    const float* beta  = (const float*)d_in[7];
    float* out = (float*)d_out;

    // ws layout (bytes):
    char* wsb = (char*)d_ws;
    unsigned short* rhB   = (unsigned short*)(wsb);                   // Gn*64*2 = 2,048,000
    unsigned short* vBg   = (unsigned short*)(wsb + 2048000);         // Bn*64*2 =   524,288
    float*          v64   = (float*)(wsb + 2572288);                  // Bn*4    =    16,384
    float*          lsp1  = (float*)(wsb + 2588672);                  // Gn*4
    float*          lsn   = (float*)(wsb + 2652672);
    float*          eps   = (float*)(wsb + 2716672);
    float*          part  = (float*)(wsb + 2780672);                  // NGT*Bn*4 = 819,200
    float*          prio  = (float*)(wsb + 3599872);                  // 64*4 = 256

    prep_fused<<<GENE_BLOCKS + SPOT_BLOCKS, 256, 0, stream>>>(
        W, px_o, eta, beta, V, ind_x, rhB, lsp1, lsn, eps, vBg, v64, prio);

    dim3 grid(NGT, Bn / BT);   // 50 x 256, gt-fastest
    main_kernel<<<grid, 256, 0, stream>>>(x, rhB, vBg, v64, lsp1, lsn, eps, part);

    reduce_kernel<<<Bn / 256, 256, 0, stream>>>(part, prio, out);
}